// Round 1
// baseline (4747.489 us; speedup 1.0000x reference)
//
#include <hip/hip_runtime.h>
#include <math.h>

#define H 8
#define O 32
#define C 256            // H*O
#define NEG_SLOPE 0.2f
#define EPS_V 1e-16f

// ---------- ordered-uint encoding for float atomicMax ----------
__device__ __forceinline__ unsigned enc_f(float x){
  unsigned u = __float_as_uint(x);
  return u ^ ((u >> 31) ? 0xFFFFFFFFu : 0x80000000u);
}
__device__ __forceinline__ float dec_f(unsigned u){
  return __uint_as_float(u ^ ((u >> 31) ? 0x80000000u : 0xFFFFFFFFu));
}

__global__ void init_max_kernel(unsigned* m){
  *m = enc_f(-3.402823466e38f);
}

// ---------- h_prime = einsum('nf,hfo->nho'), stored [n, h*32+o] ----------
template<int FIN, int TILE_N>
__global__ __launch_bounds__(256) void gemm_kernel(
    const float* __restrict__ h, const float* __restrict__ w,
    float* __restrict__ hp, int n_nodes){
  __shared__ float sh[TILE_N][FIN];
  const int c = threadIdx.x;            // 0..255 -> head=c>>5, o=c&31
  const int head = c >> 5, o = c & 31;
  const int n0 = blockIdx.x * TILE_N;
  for (int i = c; i < TILE_N * FIN; i += 256){
    int t = i / FIN, f = i - t * FIN;
    int nn = n0 + t;
    sh[t][f] = (nn < n_nodes) ? h[nn * FIN + f] : 0.f;
  }
  __syncthreads();
  float acc[TILE_N];
#pragma unroll
  for (int t = 0; t < TILE_N; ++t) acc[t] = 0.f;
  const float* wp = w + (head * FIN) * O + o;   // w[head, f, o], stride O over f
  for (int f = 0; f < FIN; ++f){
    float wv = wp[f * O];
#pragma unroll
    for (int t = 0; t < TILE_N; ++t) acc[t] = fmaf(sh[t][f], wv, acc[t]);
  }
#pragma unroll
  for (int t = 0; t < TILE_N; ++t){
    int nn = n0 + t;
    if (nn < n_nodes) hp[nn * C + c] = acc[t];
  }
}

// ---------- attn_src[n,h], attn_trg[n,h] ----------
__global__ void attn_kernel(const float* __restrict__ hp,
                            const float* __restrict__ a_src,
                            const float* __restrict__ a_trg,
                            float* __restrict__ as_, float* __restrict__ at_,
                            int nh){
  int i = blockIdx.x * 256 + threadIdx.x;
  if (i >= nh) return;
  int n = i >> 3, h = i & 7;
  const float* row = hp + n * C + h * O;
  const float* vs = a_src + h * O;
  const float* vt = a_trg + h * O;
  float s = 0.f, t = 0.f;
#pragma unroll
  for (int o = 0; o < O; ++o){
    float v = row[o];
    s = fmaf(v, vs[o], s);
    t = fmaf(v, vt[o], t);
  }
  as_[i] = s;
  at_[i] = t;
}

// ---------- global max of leaky_relu(as[src]+at[trg]) over [E,H] ----------
__global__ void max_kernel(const float* __restrict__ as_, const float* __restrict__ at_,
                           const int* __restrict__ src, const int* __restrict__ trg,
                           unsigned* __restrict__ maxbuf, int eh){
  int i = blockIdx.x * 256 + threadIdx.x;
  float v = -3.402823466e38f;
  if (i < eh){
    int e = i >> 3, h = i & 7;
    float x = as_[src[e] * H + h] + at_[trg[e] * H + h];
    v = (x >= 0.f) ? x : NEG_SLOPE * x;
  }
  for (int off = 32; off > 0; off >>= 1)
    v = fmaxf(v, __shfl_down(v, off, 64));
  __shared__ float sm[4];
  int lane = threadIdx.x & 63, wv = threadIdx.x >> 6;
  if (lane == 0) sm[wv] = v;
  __syncthreads();
  if (threadIdx.x == 0){
    float m = fmaxf(fmaxf(sm[0], sm[1]), fmaxf(sm[2], sm[3]));
    atomicMax(maxbuf, enc_f(m));
  }
}

// ---------- exp_e + denom segment-sum ----------
__global__ void edge_kernel(const float* __restrict__ as_, const float* __restrict__ at_,
                            const int* __restrict__ src, const int* __restrict__ trg,
                            const unsigned* __restrict__ maxbuf,
                            float* __restrict__ expe, float* __restrict__ denom, int eh){
  int i = blockIdx.x * 256 + threadIdx.x;
  if (i >= eh) return;
  int e = i >> 3, h = i & 7;
  float m = dec_f(*maxbuf);
  float x = as_[src[e] * H + h] + at_[trg[e] * H + h];
  x = (x >= 0.f) ? x : NEG_SLOPE * x;
  float ex = expf(x - m);
  expe[i] = ex;
  atomicAdd(&denom[trg[e] * H + h], ex);
}

// ---------- out[trg] += h_prime[src] * attn, per (edge, channel) ----------
__global__ __launch_bounds__(256) void scatter_kernel(
    const float* __restrict__ hp, const float* __restrict__ expe,
    const float* __restrict__ denom,
    const int* __restrict__ src, const int* __restrict__ trg,
    float* __restrict__ out, int E){
  int e = blockIdx.x;
  if (e >= E) return;
  int c = threadIdx.x;
  int head = c >> 5;
  int s = src[e], t = trg[e];
  float coef = expe[e * H + head] / (denom[t * H + head] + EPS_V);
  atomicAdd(&out[t * C + c], hp[s * C + c] * coef);
}

__global__ void elu_kernel(float* __restrict__ x, int n){
  int i = blockIdx.x * 256 + threadIdx.x;
  if (i >= n) return;
  float v = x[i];
  x[i] = (v > 0.f) ? v : expm1f(v);
}

__global__ void mean_kernel(const float* __restrict__ acc, float* __restrict__ emb, int no){
  int i = blockIdx.x * 256 + threadIdx.x;
  if (i >= no) return;
  int n = i >> 5, o = i & 31;
  const float* p = acc + n * C + o;
  float s = 0.f;
#pragma unroll
  for (int h = 0; h < H; ++h) s += p[h * O];
  emb[i] = s * (1.f / H);
}

__global__ void final_kernel(const float* __restrict__ e0, const float* __restrict__ e1,
                             const float* __restrict__ fw, const float* __restrict__ fb,
                             float* __restrict__ out, int n_user){
  int n = blockIdx.x * 256 + threadIdx.x;
  if (n >= n_user) return;
  float l0 = fb[0], l1 = fb[1];
  const float* p0 = e0 + n * O;
  const float* p1 = e1 + n * O;
#pragma unroll
  for (int o = 0; o < O; ++o){
    float v = p0[o];
    l0 = fmaf(v, fw[o * 2 + 0], l0);
    l1 = fmaf(v, fw[o * 2 + 1], l1);
  }
#pragma unroll
  for (int o = 0; o < O; ++o){
    float v = p1[o];
    l0 = fmaf(v, fw[(O + o) * 2 + 0], l0);
    l1 = fmaf(v, fw[(O + o) * 2 + 1], l1);
  }
  float m = fmaxf(l0, l1);
  float lse = m + logf(expf(l0 - m) + expf(l1 - m));
  out[n * 2 + 0] = l0 - lse;
  out[n * 2 + 1] = l1 - lse;
}

extern "C" void kernel_launch(void* const* d_in, const int* in_sizes, int n_in,
                              void* d_out, int out_size, void* d_ws, size_t ws_size,
                              hipStream_t stream){
  const float* h0 = (const float*)d_in[0];
  const float* h1 = (const float*)d_in[1];
  const int* src0 = (const int*)d_in[2];
  const int* trg0 = (const int*)d_in[3];
  const int* src1 = (const int*)d_in[4];
  const int* trg1 = (const int*)d_in[5];
  const float* W [2][2] = {{(const float*)d_in[6],  (const float*)d_in[9]},
                           {(const float*)d_in[12], (const float*)d_in[15]}};
  const float* AS[2][2] = {{(const float*)d_in[7],  (const float*)d_in[10]},
                           {(const float*)d_in[13], (const float*)d_in[16]}};
  const float* AT[2][2] = {{(const float*)d_in[8],  (const float*)d_in[11]},
                           {(const float*)d_in[14], (const float*)d_in[17]}};
  const float* fc_w = (const float*)d_in[18];
  const float* fc_b = (const float*)d_in[19];
  float* out = (float*)d_out;

  const int N = in_sizes[0] / 128;   // 60000
  const int E = in_sizes[2];         // 800000
  const int n_user = out_size / 2;   // 50000

  // workspace layout (fp32)
  float* ws = (float*)d_ws;
  float* hp     = ws;  ws += (size_t)N * C;       // h_prime [N,256]
  float* outacc = ws;  ws += (size_t)N * C;       // layer output accumulator [N,256]
  float* expe   = ws;  ws += (size_t)E * H;       // exp(e) [E,8]
  float* attn_s = ws;  ws += (size_t)N * H;
  float* attn_t = ws;  ws += (size_t)N * H;
  float* denom  = ws;  ws += (size_t)N * H;
  float* emb[2];
  emb[0] = ws;         ws += (size_t)N * O;
  emb[1] = ws;         ws += (size_t)N * O;
  unsigned* maxbuf = (unsigned*)ws;

  const float* hin [2] = {h0, h1};
  const int*   srcs[2] = {src0, src1};
  const int*   trgs[2] = {trg0, trg1};

  const int nh = N * H;
  const int eh = E * H;

  for (int s = 0; s < 2; ++s){
    const int* src = srcs[s];
    const int* trg = trgs[s];
    for (int l = 0; l < 2; ++l){
      // 1. GEMM: h_prime
      if (l == 0)
        gemm_kernel<128,16><<<(N + 15) / 16, 256, 0, stream>>>(hin[s], W[s][0], hp, N);
      else
        gemm_kernel<256,16><<<(N + 15) / 16, 256, 0, stream>>>(outacc, W[s][1], hp, N);
      // 2. per-node attention logits
      attn_kernel<<<(nh + 255) / 256, 256, 0, stream>>>(hp, AS[s][l], AT[s][l],
                                                        attn_s, attn_t, nh);
      // 3. global max (for the reference's max-shift)
      init_max_kernel<<<1, 1, 0, stream>>>(maxbuf);
      max_kernel<<<(eh + 255) / 256, 256, 0, stream>>>(attn_s, attn_t, src, trg,
                                                       maxbuf, eh);
      // 4. exp + denominator segment-sum
      hipMemsetAsync(denom, 0, (size_t)N * H * sizeof(float), stream);
      edge_kernel<<<(eh + 255) / 256, 256, 0, stream>>>(attn_s, attn_t, src, trg,
                                                        maxbuf, expe, denom, eh);
      // 5. weighted scatter into outacc (zero after gemm consumed it)
      hipMemsetAsync(outacc, 0, (size_t)N * C * sizeof(float), stream);
      scatter_kernel<<<E, 256, 0, stream>>>(hp, expe, denom, src, trg, outacc, E);
      // 6. epilogue
      if (l == 0)
        elu_kernel<<<((N * C) + 255) / 256, 256, 0, stream>>>(outacc, N * C);
      else
        mean_kernel<<<((N * O) + 255) / 256, 256, 0, stream>>>(outacc, emb[s], N * O);
    }
  }

  final_kernel<<<(n_user + 255) / 256, 256, 0, stream>>>(emb[0], emb[1], fc_w, fc_b,
                                                         out, n_user);
}

// Round 2
// 2871.436 us; speedup vs baseline: 1.6534x; 1.6534x over previous
//
#include <hip/hip_runtime.h>
#include <math.h>

#define H 8
#define O 32
#define C 256            // H*O
#define NEG_SLOPE 0.2f
#define EPS_V 1e-16f

// ---------- ordered-uint encoding for float atomicMax ----------
__device__ __forceinline__ unsigned enc_f(float x){
  unsigned u = __float_as_uint(x);
  return u ^ ((u >> 31) ? 0xFFFFFFFFu : 0x80000000u);
}
__device__ __forceinline__ float dec_f(unsigned u){
  return __uint_as_float(u ^ ((u >> 31) ? 0x80000000u : 0xFFFFFFFFu));
}

__global__ void init_max_kernel(unsigned* m){
  *m = enc_f(-3.402823466e38f);
}

// ---------- CSR build ----------
__global__ void count_kernel(const int* __restrict__ trg, int* __restrict__ deg, int E){
  int e = blockIdx.x * 256 + threadIdx.x;
  if (e < E) atomicAdd(&deg[trg[e]], 1);
}

// single-block exclusive scan: row_ptr[0]=0, row_ptr[i]=sum(deg[0..i-1])
__global__ void scan_kernel(const int* __restrict__ deg, int* __restrict__ row_ptr, int n){
  __shared__ int sm[1024];
  int run = 0;
  if (threadIdx.x == 0) row_ptr[0] = 0;
  for (int base = 0; base < n; base += 1024){
    int i = base + threadIdx.x;
    int v = (i < n) ? deg[i] : 0;
    sm[threadIdx.x] = v;
    __syncthreads();
    for (int off = 1; off < 1024; off <<= 1){
      int t = (threadIdx.x >= off) ? sm[threadIdx.x - off] : 0;
      __syncthreads();
      sm[threadIdx.x] += t;
      __syncthreads();
    }
    if (i < n) row_ptr[i + 1] = run + sm[threadIdx.x];
    run += sm[1023];
    __syncthreads();
  }
}

__global__ void fill_kernel(const int* __restrict__ trg, const int* __restrict__ row_ptr,
                            int* __restrict__ cursor, int* __restrict__ eidx, int E){
  int e = blockIdx.x * 256 + threadIdx.x;
  if (e >= E) return;
  int t = trg[e];
  int p = atomicAdd(&cursor[t], 1);
  eidx[row_ptr[t] + p] = e;
}

// ---------- h_prime = einsum('nf,hfo->nho'), stored [n, h*32+o] ----------
template<int FIN, int TILE_N>
__global__ __launch_bounds__(256) void gemm_kernel(
    const float* __restrict__ h, const float* __restrict__ w,
    float* __restrict__ hp, int n_nodes){
  __shared__ float sh[TILE_N][FIN];
  const int c = threadIdx.x;            // 0..255 -> head=c>>5, o=c&31
  const int head = c >> 5, o = c & 31;
  const int n0 = blockIdx.x * TILE_N;
  for (int i = c; i < TILE_N * FIN; i += 256){
    int t = i / FIN, f = i - t * FIN;
    int nn = n0 + t;
    sh[t][f] = (nn < n_nodes) ? h[nn * FIN + f] : 0.f;
  }
  __syncthreads();
  float acc[TILE_N];
#pragma unroll
  for (int t = 0; t < TILE_N; ++t) acc[t] = 0.f;
  const float* wp = w + (head * FIN) * O + o;   // w[head, f, o], stride O over f
  for (int f = 0; f < FIN; ++f){
    float wv = wp[f * O];
#pragma unroll
    for (int t = 0; t < TILE_N; ++t) acc[t] = fmaf(sh[t][f], wv, acc[t]);
  }
#pragma unroll
  for (int t = 0; t < TILE_N; ++t){
    int nn = n0 + t;
    if (nn < n_nodes) hp[nn * C + c] = acc[t];
  }
}

// ---------- attn_src[n,h], attn_trg[n,h] ----------
__global__ void attn_kernel(const float* __restrict__ hp,
                            const float* __restrict__ a_src,
                            const float* __restrict__ a_trg,
                            float* __restrict__ as_, float* __restrict__ at_,
                            int nh){
  int i = blockIdx.x * 256 + threadIdx.x;
  if (i >= nh) return;
  int n = i >> 3, h = i & 7;
  const float* row = hp + n * C + h * O;
  const float* vs = a_src + h * O;
  const float* vt = a_trg + h * O;
  float s = 0.f, t = 0.f;
#pragma unroll
  for (int o = 0; o < O; ++o){
    float v = row[o];
    s = fmaf(v, vs[o], s);
    t = fmaf(v, vt[o], t);
  }
  as_[i] = s;
  at_[i] = t;
}

// ---------- global max of leaky_relu(as[src]+at[trg]) over [E,H] ----------
__global__ void max_kernel(const float* __restrict__ as_, const float* __restrict__ at_,
                           const int* __restrict__ src, const int* __restrict__ trg,
                           unsigned* __restrict__ maxbuf, int eh){
  int i = blockIdx.x * 256 + threadIdx.x;
  float v = -3.402823466e38f;
  if (i < eh){
    int e = i >> 3, h = i & 7;
    float x = as_[src[e] * H + h] + at_[trg[e] * H + h];
    v = (x >= 0.f) ? x : NEG_SLOPE * x;
  }
  for (int off = 32; off > 0; off >>= 1)
    v = fmaxf(v, __shfl_down(v, off, 64));
  __shared__ float sm[4];
  int lane = threadIdx.x & 63, wv = threadIdx.x >> 6;
  if (lane == 0) sm[wv] = v;
  __syncthreads();
  if (threadIdx.x == 0){
    float m = fmaxf(fmaxf(sm[0], sm[1]), fmaxf(sm[2], sm[3]));
    atomicMax(maxbuf, enc_f(m));
  }
}

// ---------- exp_e (no atomics; denom folded into gather) ----------
__global__ void edge_kernel(const float* __restrict__ as_, const float* __restrict__ at_,
                            const int* __restrict__ src, const int* __restrict__ trg,
                            const unsigned* __restrict__ maxbuf,
                            float* __restrict__ expe, int eh){
  int i = blockIdx.x * 256 + threadIdx.x;
  if (i >= eh) return;
  int e = i >> 3, h = i & 7;
  float m = dec_f(*maxbuf);
  float x = as_[src[e] * H + h] + at_[trg[e] * H + h];
  x = (x >= 0.f) ? x : NEG_SLOPE * x;
  expe[i] = expf(x - m);
}

// ---------- CSR gather: one wave per destination node ----------
// lane handles channels 4*lane .. 4*lane+3  (head = lane>>3)
// MODE 0: store elu(acc/denom) to out[n,256]
// MODE 1: head-mean -> emb[n,32]
template<int MODE>
__global__ __launch_bounds__(256) void gather_kernel(
    const float* __restrict__ hp, const float* __restrict__ expe,
    const int* __restrict__ src, const int* __restrict__ row_ptr,
    const int* __restrict__ eidx, float* __restrict__ out, int n_nodes){
  int wid = (blockIdx.x * 256 + threadIdx.x) >> 6;
  if (wid >= n_nodes) return;
  int lane = threadIdx.x & 63;
  int head = lane >> 3;
  int beg = row_ptr[wid], end = row_ptr[wid + 1];
  float4 acc = {0.f, 0.f, 0.f, 0.f};
  float dsum = 0.f;
  for (int j = beg; j < end; ++j){
    int e = eidx[j];
    float ex = expe[e * H + head];
    int s = src[e];
    const float4 v = *(const float4*)(hp + (size_t)s * C + lane * 4);
    dsum += ex;
    acc.x = fmaf(v.x, ex, acc.x);
    acc.y = fmaf(v.y, ex, acc.y);
    acc.z = fmaf(v.z, ex, acc.z);
    acc.w = fmaf(v.w, ex, acc.w);
  }
  float inv = 1.f / (dsum + EPS_V);
  acc.x *= inv; acc.y *= inv; acc.z *= inv; acc.w *= inv;
  if (MODE == 0){
    float4 r;
    r.x = (acc.x > 0.f) ? acc.x : expm1f(acc.x);
    r.y = (acc.y > 0.f) ? acc.y : expm1f(acc.y);
    r.z = (acc.z > 0.f) ? acc.z : expm1f(acc.z);
    r.w = (acc.w > 0.f) ? acc.w : expm1f(acc.w);
    *(float4*)(out + (size_t)wid * C + lane * 4) = r;
  } else {
    // mean over heads: channel c and c+32 differ by 8 lanes
#pragma unroll
    for (int mask = 8; mask <= 32; mask <<= 1){
      acc.x += __shfl_xor(acc.x, mask, 64);
      acc.y += __shfl_xor(acc.y, mask, 64);
      acc.z += __shfl_xor(acc.z, mask, 64);
      acc.w += __shfl_xor(acc.w, mask, 64);
    }
    if (lane < 8){
      float4 r;
      r.x = acc.x * 0.125f; r.y = acc.y * 0.125f;
      r.z = acc.z * 0.125f; r.w = acc.w * 0.125f;
      *(float4*)(out + (size_t)wid * O + lane * 4) = r;
    }
  }
}

__global__ void final_kernel(const float* __restrict__ e0, const float* __restrict__ e1,
                             const float* __restrict__ fw, const float* __restrict__ fb,
                             float* __restrict__ out, int n_user){
  int n = blockIdx.x * 256 + threadIdx.x;
  if (n >= n_user) return;
  float l0 = fb[0], l1 = fb[1];
  const float* p0 = e0 + n * O;
  const float* p1 = e1 + n * O;
#pragma unroll
  for (int o = 0; o < O; ++o){
    float v = p0[o];
    l0 = fmaf(v, fw[o * 2 + 0], l0);
    l1 = fmaf(v, fw[o * 2 + 1], l1);
  }
#pragma unroll
  for (int o = 0; o < O; ++o){
    float v = p1[o];
    l0 = fmaf(v, fw[(O + o) * 2 + 0], l0);
    l1 = fmaf(v, fw[(O + o) * 2 + 1], l1);
  }
  float m = fmaxf(l0, l1);
  float lse = m + logf(expf(l0 - m) + expf(l1 - m));
  out[n * 2 + 0] = l0 - lse;
  out[n * 2 + 1] = l1 - lse;
}

extern "C" void kernel_launch(void* const* d_in, const int* in_sizes, int n_in,
                              void* d_out, int out_size, void* d_ws, size_t ws_size,
                              hipStream_t stream){
  const float* h0 = (const float*)d_in[0];
  const float* h1 = (const float*)d_in[1];
  const int* src0 = (const int*)d_in[2];
  const int* trg0 = (const int*)d_in[3];
  const int* src1 = (const int*)d_in[4];
  const int* trg1 = (const int*)d_in[5];
  const float* W [2][2] = {{(const float*)d_in[6],  (const float*)d_in[9]},
                           {(const float*)d_in[12], (const float*)d_in[15]}};
  const float* AS[2][2] = {{(const float*)d_in[7],  (const float*)d_in[10]},
                           {(const float*)d_in[13], (const float*)d_in[16]}};
  const float* AT[2][2] = {{(const float*)d_in[8],  (const float*)d_in[11]},
                           {(const float*)d_in[14], (const float*)d_in[17]}};
  const float* fc_w = (const float*)d_in[18];
  const float* fc_b = (const float*)d_in[19];
  float* out = (float*)d_out;

  const int N = in_sizes[0] / 128;   // 60000
  const int E = in_sizes[2];         // 800000
  const int n_user = out_size / 2;   // 50000

  // workspace layout (fp32 / int32)
  float* ws = (float*)d_ws;
  float* hp     = ws;  ws += (size_t)N * C;       // h_prime [N,256]
  float* outacc = ws;  ws += (size_t)N * C;       // layer-1 output [N,256]
  float* expe   = ws;  ws += (size_t)E * H;       // exp(e) [E,8]
  float* attn_s = ws;  ws += (size_t)N * H;
  float* attn_t = ws;  ws += (size_t)N * H;
  float* emb[2];
  emb[0] = ws;         ws += (size_t)n_user * O;
  emb[1] = ws;         ws += (size_t)n_user * O;
  int* row_ptr = (int*)ws;  ws += (size_t)(N + 1);
  int* eidx    = (int*)ws;  ws += (size_t)E;
  int* cursor  = (int*)ws;  ws += (size_t)N;
  unsigned* maxbuf = (unsigned*)ws;

  const float* hin [2] = {h0, h1};
  const int*   srcs[2] = {src0, src1};
  const int*   trgs[2] = {trg0, trg1};

  const int nh = N * H;
  const int eh = E * H;

  for (int s = 0; s < 2; ++s){
    const int* src = srcs[s];
    const int* trg = trgs[s];

    // --- CSR build by trg (reused by both layers) ---
    hipMemsetAsync(cursor, 0, (size_t)N * sizeof(int), stream);
    count_kernel<<<(E + 255) / 256, 256, 0, stream>>>(trg, cursor, E);
    scan_kernel<<<1, 1024, 0, stream>>>(cursor, row_ptr, N);
    hipMemsetAsync(cursor, 0, (size_t)N * sizeof(int), stream);
    fill_kernel<<<(E + 255) / 256, 256, 0, stream>>>(trg, row_ptr, cursor, eidx, E);

    for (int l = 0; l < 2; ++l){
      // 1. GEMM: h_prime
      if (l == 0)
        gemm_kernel<128,16><<<(N + 15) / 16, 256, 0, stream>>>(hin[s], W[s][0], hp, N);
      else
        gemm_kernel<256,16><<<(N + 15) / 16, 256, 0, stream>>>(outacc, W[s][1], hp, N);
      // 2. per-node attention logits
      attn_kernel<<<(nh + 255) / 256, 256, 0, stream>>>(hp, AS[s][l], AT[s][l],
                                                        attn_s, attn_t, nh);
      // 3. global max (for the reference's max-shift)
      init_max_kernel<<<1, 1, 0, stream>>>(maxbuf);
      max_kernel<<<(eh + 255) / 256, 256, 0, stream>>>(attn_s, attn_t, src, trg,
                                                       maxbuf, eh);
      // 4. exp(e)
      edge_kernel<<<(eh + 255) / 256, 256, 0, stream>>>(attn_s, attn_t, src, trg,
                                                        maxbuf, expe, eh);
      // 5. CSR gather (fused normalize + epilogue)
      if (l == 0)
        gather_kernel<0><<<(N * 64 + 255) / 256, 256, 0, stream>>>(
            hp, expe, src, row_ptr, eidx, outacc, N);
      else
        gather_kernel<1><<<(n_user * 64 + 255) / 256, 256, 0, stream>>>(
            hp, expe, src, row_ptr, eidx, emb[s], n_user);
    }
  }

  final_kernel<<<(n_user + 255) / 256, 256, 0, stream>>>(emb[0], emb[1], fc_w, fc_b,
                                                         out, n_user);
}

// Round 3
// 1829.160 us; speedup vs baseline: 2.5954x; 1.5698x over previous
//
#include <hip/hip_runtime.h>
#include <math.h>

#define H 8
#define O 32
#define C 256            // H*O
#define NEG_SLOPE 0.2f
#define EPS_V 1e-16f

// ---------- ordered-uint encoding for float atomicMax ----------
__device__ __forceinline__ unsigned enc_f(float x){
  unsigned u = __float_as_uint(x);
  return u ^ ((u >> 31) ? 0xFFFFFFFFu : 0x80000000u);
}
__device__ __forceinline__ float dec_f(unsigned u){
  return __uint_as_float(u ^ ((u >> 31) ? 0x80000000u : 0xFFFFFFFFu));
}

__global__ void init_max_kernel(unsigned* m){
  *m = enc_f(-3.402823466e38f);
}

// ---------- CSR build ----------
__global__ void count_kernel(const int* __restrict__ trg, int* __restrict__ deg, int E){
  int e = blockIdx.x * 256 + threadIdx.x;
  if (e < E) atomicAdd(&deg[trg[e]], 1);
}

// single-block exclusive scan: row_ptr[0]=0, row_ptr[i]=sum(deg[0..i-1])
__global__ void scan_kernel(const int* __restrict__ deg, int* __restrict__ row_ptr, int n){
  __shared__ int sm[1024];
  int run = 0;
  if (threadIdx.x == 0) row_ptr[0] = 0;
  for (int base = 0; base < n; base += 1024){
    int i = base + threadIdx.x;
    int v = (i < n) ? deg[i] : 0;
    sm[threadIdx.x] = v;
    __syncthreads();
    for (int off = 1; off < 1024; off <<= 1){
      int t = (threadIdx.x >= off) ? sm[threadIdx.x - off] : 0;
      __syncthreads();
      sm[threadIdx.x] += t;
      __syncthreads();
    }
    if (i < n) row_ptr[i + 1] = run + sm[threadIdx.x];
    run += sm[1023];
    __syncthreads();
  }
}

__global__ void fill_kernel(const int* __restrict__ trg, const int* __restrict__ row_ptr,
                            int* __restrict__ cursor, int* __restrict__ eidx, int E){
  int e = blockIdx.x * 256 + threadIdx.x;
  if (e >= E) return;
  int t = trg[e];
  int p = atomicAdd(&cursor[t], 1);
  eidx[row_ptr[t] + p] = e;
}

// ---------- h_prime = einsum('nf,hfo->nho'), stored [n, h*32+o] ----------
template<int FIN, int TILE_N>
__global__ __launch_bounds__(256) void gemm_kernel(
    const float* __restrict__ h, const float* __restrict__ w,
    float* __restrict__ hp, int n_nodes){
  __shared__ float sh[TILE_N][FIN];
  const int c = threadIdx.x;            // 0..255 -> head=c>>5, o=c&31
  const int head = c >> 5, o = c & 31;
  const int n0 = blockIdx.x * TILE_N;
  for (int i = c; i < TILE_N * FIN; i += 256){
    int t = i / FIN, f = i - t * FIN;
    int nn = n0 + t;
    sh[t][f] = (nn < n_nodes) ? h[nn * FIN + f] : 0.f;
  }
  __syncthreads();
  float acc[TILE_N];
#pragma unroll
  for (int t = 0; t < TILE_N; ++t) acc[t] = 0.f;
  const float* wp = w + (head * FIN) * O + o;   // w[head, f, o], stride O over f
  for (int f = 0; f < FIN; ++f){
    float wv = wp[f * O];
#pragma unroll
    for (int t = 0; t < TILE_N; ++t) acc[t] = fmaf(sh[t][f], wv, acc[t]);
  }
#pragma unroll
  for (int t = 0; t < TILE_N; ++t){
    int nn = n0 + t;
    if (nn < n_nodes) hp[nn * C + c] = acc[t];
  }
}

// ---------- attn_src[n,h], attn_trg[n,h] ----------
__global__ void attn_kernel(const float* __restrict__ hp,
                            const float* __restrict__ a_src,
                            const float* __restrict__ a_trg,
                            float* __restrict__ as_, float* __restrict__ at_,
                            int nh){
  int i = blockIdx.x * 256 + threadIdx.x;
  if (i >= nh) return;
  int n = i >> 3, h = i & 7;
  const float* row = hp + n * C + h * O;
  const float* vs = a_src + h * O;
  const float* vt = a_trg + h * O;
  float s = 0.f, t = 0.f;
#pragma unroll
  for (int o = 0; o < O; ++o){
    float v = row[o];
    s = fmaf(v, vs[o], s);
    t = fmaf(v, vt[o], t);
  }
  as_[i] = s;
  at_[i] = t;
}

// ---------- global max of leaky_relu(as[src]+at[trg]) over [E,H] ----------
// grid-stride, one atomic per block (single-address atomic contention was
// 288us/dispatch at 25000 blocks -> 1024 blocks fixes it)
__global__ __launch_bounds__(256) void max_kernel(
    const float* __restrict__ as_, const float* __restrict__ at_,
    const int* __restrict__ src, const int* __restrict__ trg,
    unsigned* __restrict__ maxbuf, int eh){
  float v = -3.402823466e38f;
  for (int i = blockIdx.x * 256 + threadIdx.x; i < eh; i += gridDim.x * 256){
    int e = i >> 3, h = i & 7;
    float x = as_[src[e] * H + h] + at_[trg[e] * H + h];
    x = (x >= 0.f) ? x : NEG_SLOPE * x;
    v = fmaxf(v, x);
  }
  for (int off = 32; off > 0; off >>= 1)
    v = fmaxf(v, __shfl_down(v, off, 64));
  __shared__ float sm[4];
  int lane = threadIdx.x & 63, wv = threadIdx.x >> 6;
  if (lane == 0) sm[wv] = v;
  __syncthreads();
  if (threadIdx.x == 0){
    float m = fmaxf(fmaxf(sm[0], sm[1]), fmaxf(sm[2], sm[3]));
    atomicMax(maxbuf, enc_f(m));
  }
}

// ---------- exp_e (no atomics; denom folded into gather) ----------
__global__ void edge_kernel(const float* __restrict__ as_, const float* __restrict__ at_,
                            const int* __restrict__ src, const int* __restrict__ trg,
                            const unsigned* __restrict__ maxbuf,
                            float* __restrict__ expe, int eh){
  int i = blockIdx.x * 256 + threadIdx.x;
  if (i >= eh) return;
  int e = i >> 3, h = i & 7;
  float m = dec_f(*maxbuf);
  float x = as_[src[e] * H + h] + at_[trg[e] * H + h];
  x = (x >= 0.f) ? x : NEG_SLOPE * x;
  expe[i] = expf(x - m);
}

// ---------- CSR gather: one wave per destination node ----------
// lane handles channels 4*lane .. 4*lane+3  (head = lane>>3)
// MODE 0: store elu(acc/denom) to out[n,256]
// MODE 1: head-mean -> emb[n,32]
template<int MODE>
__global__ __launch_bounds__(256) void gather_kernel(
    const float* __restrict__ hp, const float* __restrict__ expe,
    const int* __restrict__ src, const int* __restrict__ row_ptr,
    const int* __restrict__ eidx, float* __restrict__ out, int n_nodes){
  int wid = (blockIdx.x * 256 + threadIdx.x) >> 6;
  if (wid >= n_nodes) return;
  int lane = threadIdx.x & 63;
  int head = lane >> 3;
  int beg = row_ptr[wid], end = row_ptr[wid + 1];
  float4 acc = {0.f, 0.f, 0.f, 0.f};
  float dsum = 0.f;
  for (int j = beg; j < end; ++j){
    int e = eidx[j];
    float ex = expe[e * H + head];
    int s = src[e];
    const float4 v = *(const float4*)(hp + (size_t)s * C + lane * 4);
    dsum += ex;
    acc.x = fmaf(v.x, ex, acc.x);
    acc.y = fmaf(v.y, ex, acc.y);
    acc.z = fmaf(v.z, ex, acc.z);
    acc.w = fmaf(v.w, ex, acc.w);
  }
  float inv = 1.f / (dsum + EPS_V);
  acc.x *= inv; acc.y *= inv; acc.z *= inv; acc.w *= inv;
  if (MODE == 0){
    float4 r;
    r.x = (acc.x > 0.f) ? acc.x : expm1f(acc.x);
    r.y = (acc.y > 0.f) ? acc.y : expm1f(acc.y);
    r.z = (acc.z > 0.f) ? acc.z : expm1f(acc.z);
    r.w = (acc.w > 0.f) ? acc.w : expm1f(acc.w);
    *(float4*)(out + (size_t)wid * C + lane * 4) = r;
  } else {
    // mean over heads: channel c and c+32 differ by 8 lanes
#pragma unroll
    for (int mask = 8; mask <= 32; mask <<= 1){
      acc.x += __shfl_xor(acc.x, mask, 64);
      acc.y += __shfl_xor(acc.y, mask, 64);
      acc.z += __shfl_xor(acc.z, mask, 64);
      acc.w += __shfl_xor(acc.w, mask, 64);
    }
    if (lane < 8){
      float4 r;
      r.x = acc.x * 0.125f; r.y = acc.y * 0.125f;
      r.z = acc.z * 0.125f; r.w = acc.w * 0.125f;
      *(float4*)(out + (size_t)wid * O + lane * 4) = r;
    }
  }
}

__global__ void final_kernel(const float* __restrict__ e0, const float* __restrict__ e1,
                             const float* __restrict__ fw, const float* __restrict__ fb,
                             float* __restrict__ out, int n_user){
  int n = blockIdx.x * 256 + threadIdx.x;
  if (n >= n_user) return;
  float l0 = fb[0], l1 = fb[1];
  const float* p0 = e0 + n * O;
  const float* p1 = e1 + n * O;
#pragma unroll
  for (int o = 0; o < O; ++o){
    float v = p0[o];
    l0 = fmaf(v, fw[o * 2 + 0], l0);
    l1 = fmaf(v, fw[o * 2 + 1], l1);
  }
#pragma unroll
  for (int o = 0; o < O; ++o){
    float v = p1[o];
    l0 = fmaf(v, fw[(O + o) * 2 + 0], l0);
    l1 = fmaf(v, fw[(O + o) * 2 + 1], l1);
  }
  float m = fmaxf(l0, l1);
  float lse = m + logf(expf(l0 - m) + expf(l1 - m));
  out[n * 2 + 0] = l0 - lse;
  out[n * 2 + 1] = l1 - lse;
}

extern "C" void kernel_launch(void* const* d_in, const int* in_sizes, int n_in,
                              void* d_out, int out_size, void* d_ws, size_t ws_size,
                              hipStream_t stream){
  const float* h0 = (const float*)d_in[0];
  const float* h1 = (const float*)d_in[1];
  const int* src0 = (const int*)d_in[2];
  const int* trg0 = (const int*)d_in[3];
  const int* src1 = (const int*)d_in[4];
  const int* trg1 = (const int*)d_in[5];
  const float* W [2][2] = {{(const float*)d_in[6],  (const float*)d_in[9]},
                           {(const float*)d_in[12], (const float*)d_in[15]}};
  const float* AS[2][2] = {{(const float*)d_in[7],  (const float*)d_in[10]},
                           {(const float*)d_in[13], (const float*)d_in[16]}};
  const float* AT[2][2] = {{(const float*)d_in[8],  (const float*)d_in[11]},
                           {(const float*)d_in[14], (const float*)d_in[17]}};
  const float* fc_w = (const float*)d_in[18];
  const float* fc_b = (const float*)d_in[19];
  float* out = (float*)d_out;

  const int N = in_sizes[0] / 128;   // 60000
  const int E = in_sizes[2];         // 800000
  const int n_user = out_size / 2;   // 50000

  // workspace layout (fp32 / int32)
  float* ws = (float*)d_ws;
  float* hp     = ws;  ws += (size_t)N * C;       // h_prime [N,256]
  float* outacc = ws;  ws += (size_t)N * C;       // layer-1 output [N,256]
  float* expe   = ws;  ws += (size_t)E * H;       // exp(e) [E,8]
  float* attn_s = ws;  ws += (size_t)N * H;
  float* attn_t = ws;  ws += (size_t)N * H;
  float* emb[2];
  emb[0] = ws;         ws += (size_t)n_user * O;
  emb[1] = ws;         ws += (size_t)n_user * O;
  int* row_ptr = (int*)ws;  ws += (size_t)(N + 1);
  int* eidx    = (int*)ws;  ws += (size_t)E;
  int* cursor  = (int*)ws;  ws += (size_t)N;
  unsigned* maxbuf = (unsigned*)ws;

  const float* hin [2] = {h0, h1};
  const int*   srcs[2] = {src0, src1};
  const int*   trgs[2] = {trg0, trg1};

  const int nh = N * H;
  const int eh = E * H;

  for (int s = 0; s < 2; ++s){
    const int* src = srcs[s];
    const int* trg = trgs[s];

    // --- CSR build by trg (reused by both layers) ---
    hipMemsetAsync(cursor, 0, (size_t)N * sizeof(int), stream);
    count_kernel<<<(E + 255) / 256, 256, 0, stream>>>(trg, cursor, E);
    scan_kernel<<<1, 1024, 0, stream>>>(cursor, row_ptr, N);
    hipMemsetAsync(cursor, 0, (size_t)N * sizeof(int), stream);
    fill_kernel<<<(E + 255) / 256, 256, 0, stream>>>(trg, row_ptr, cursor, eidx, E);

    for (int l = 0; l < 2; ++l){
      // 1. GEMM: h_prime
      if (l == 0)
        gemm_kernel<128,16><<<(N + 15) / 16, 256, 0, stream>>>(hin[s], W[s][0], hp, N);
      else
        gemm_kernel<256,16><<<(N + 15) / 16, 256, 0, stream>>>(outacc, W[s][1], hp, N);
      // 2. per-node attention logits
      attn_kernel<<<(nh + 255) / 256, 256, 0, stream>>>(hp, AS[s][l], AT[s][l],
                                                        attn_s, attn_t, nh);
      // 3. global max (for the reference's max-shift)
      init_max_kernel<<<1, 1, 0, stream>>>(maxbuf);
      max_kernel<<<1024, 256, 0, stream>>>(attn_s, attn_t, src, trg, maxbuf, eh);
      // 4. exp(e)
      edge_kernel<<<(eh + 255) / 256, 256, 0, stream>>>(attn_s, attn_t, src, trg,
                                                        maxbuf, expe, eh);
      // 5. CSR gather (fused normalize + epilogue)
      if (l == 0)
        gather_kernel<0><<<(N * 64 + 255) / 256, 256, 0, stream>>>(
            hp, expe, src, row_ptr, eidx, outacc, N);
      else
        gather_kernel<1><<<(n_user * 64 + 255) / 256, 256, 0, stream>>>(
            hp, expe, src, row_ptr, eidx, emb[s], n_user);
    }
  }

  final_kernel<<<(n_user + 255) / 256, 256, 0, stream>>>(emb[0], emb[1], fc_w, fc_b,
                                                         out, n_user);
}

// Round 4
// 1497.250 us; speedup vs baseline: 3.1708x; 1.2217x over previous
//
#include <hip/hip_runtime.h>
#include <math.h>

#define H 8
#define O 32
#define C 256            // H*O
#define NEG_SLOPE 0.2f
#define EPS_V 1e-16f

typedef float f32x4 __attribute__((ext_vector_type(4)));
typedef short bf16x8 __attribute__((ext_vector_type(8)));

__device__ __forceinline__ unsigned short f2bf(float x){
  unsigned u = __float_as_uint(x);
  unsigned r = (u + 0x7fffu + ((u >> 16) & 1u)) >> 16;   // RNE
  return (unsigned short)r;
}

// ---------- ordered-uint encoding for float atomicMax ----------
__device__ __forceinline__ unsigned enc_f(float x){
  unsigned u = __float_as_uint(x);
  return u ^ ((u >> 31) ? 0xFFFFFFFFu : 0x80000000u);
}
__device__ __forceinline__ float dec_f(unsigned u){
  return __uint_as_float(u ^ ((u >> 31) ? 0x80000000u : 0xFFFFFFFFu));
}

__global__ void init_max_kernel(unsigned* m){
  *m = enc_f(-3.402823466e38f);
}

// ---------- CSR build ----------
__global__ void count_kernel(const int* __restrict__ trg, int* __restrict__ deg, int E){
  int e = blockIdx.x * 256 + threadIdx.x;
  if (e < E) atomicAdd(&deg[trg[e]], 1);
}

__global__ void scan_kernel(const int* __restrict__ deg, int* __restrict__ row_ptr, int n){
  __shared__ int sm[1024];
  int run = 0;
  if (threadIdx.x == 0) row_ptr[0] = 0;
  for (int base = 0; base < n; base += 1024){
    int i = base + threadIdx.x;
    int v = (i < n) ? deg[i] : 0;
    sm[threadIdx.x] = v;
    __syncthreads();
    for (int off = 1; off < 1024; off <<= 1){
      int t = (threadIdx.x >= off) ? sm[threadIdx.x - off] : 0;
      __syncthreads();
      sm[threadIdx.x] += t;
      __syncthreads();
    }
    if (i < n) row_ptr[i + 1] = run + sm[threadIdx.x];
    run += sm[1023];
    __syncthreads();
  }
}

__global__ void fill_kernel(const int* __restrict__ trg, const int* __restrict__ row_ptr,
                            int* __restrict__ cursor, int* __restrict__ eidx, int E){
  int e = blockIdx.x * 256 + threadIdx.x;
  if (e >= E) return;
  int t = trg[e];
  int p = atomicAdd(&cursor[t], 1);
  eidx[row_ptr[t] + p] = e;
}

// ---------- A-operand conversion: fp32 [N,F] row-major -> bf16 mfma-frag layout ----------
// frag layout: elem (row, k) at [rt = row>>4][kb = k>>3][m = row&15][j = k&7]
// lane's 16B a-frag = dst + ((rt*KB + kb)*16 + m)*8  (contiguous per lane)
template<int F>
__global__ void cvt_a_kernel(const float* __restrict__ src, short* __restrict__ dst,
                             int n_nodes, int total){
  constexpr int KB = F / 8;
  int t = blockIdx.x * 256 + threadIdx.x;
  if (t >= total) return;
  int kb = t % KB;
  int m  = (t / KB) & 15;
  int rt = t / (KB * 16);
  int row = rt * 16 + m;
  float v[8];
  if (row < n_nodes){
    const float4 p0 = *(const float4*)(src + (size_t)row * F + kb * 8);
    const float4 p1 = *(const float4*)(src + (size_t)row * F + kb * 8 + 4);
    v[0]=p0.x; v[1]=p0.y; v[2]=p0.z; v[3]=p0.w;
    v[4]=p1.x; v[5]=p1.y; v[6]=p1.z; v[7]=p1.w;
  } else {
    for (int j = 0; j < 8; ++j) v[j] = 0.f;
  }
  bf16x8 o;
  for (int j = 0; j < 8; ++j) o[j] = (short)f2bf(v[j]);
  *(bf16x8*)(dst + (((size_t)rt * KB + kb) * 16 + m) * 8) = o;
}

// ---------- B-operand conversion: w[h][f][o] fp32 -> bf16 frag layout ----------
// elem (k=f, col=h*32+o) at [kb][col][j]; lane's 16B b-frag = wb + ((kb*256 + col)*8)
template<int F>
__global__ void cvt_w_kernel(const float* __restrict__ w, short* __restrict__ wb){
  constexpr int KB = F / 8;
  int t = blockIdx.x * 256 + threadIdx.x;
  if (t >= 256 * KB) return;
  int c = t & 255, kb = t >> 8;
  int h = c >> 5, o = c & 31;
  bf16x8 out;
  for (int j = 0; j < 8; ++j){
    int f = kb * 8 + j;
    out[j] = (short)f2bf(w[((size_t)h * F + f) * O + o]);
  }
  *(bf16x8*)(wb + ((size_t)kb * 256 + c) * 8) = out;
}

// ---------- MFMA GEMM: hp[N,256] = A[N,F] @ W[F,256], no LDS / no barriers ----------
// block = 4 waves, 128 rows; wave = 32 rows x 256 cols (2x16 16x16 tiles)
template<int F>
__global__ __launch_bounds__(256) void gemm_mfma(
    const short* __restrict__ hb, const short* __restrict__ wb,
    float* __restrict__ hp, int n_nodes){
  constexpr int KB = F / 8;
  const int w = threadIdx.x >> 6, l = threadIdx.x & 63;
  const int q = l >> 4, m15 = l & 15;
  const int row0 = blockIdx.x * 128 + w * 32;
  const size_t rt0 = row0 >> 4;
  f32x4 acc[2][16] = {};
  for (int kk = 0; kk < F / 32; ++kk){
    const int kb0 = kk * 4 + q;
    bf16x8 a0 = *(const bf16x8*)(hb + ((rt0 * KB + kb0) * 16 + m15) * 8);
    bf16x8 a1 = *(const bf16x8*)(hb + (((rt0 + 1) * KB + kb0) * 16 + m15) * 8);
    const short* wp = wb + ((size_t)kb0 * 256 + m15) * 8;
#pragma unroll
    for (int ct = 0; ct < 16; ++ct){
      bf16x8 b = *(const bf16x8*)(wp + ct * 128);
      acc[0][ct] = __builtin_amdgcn_mfma_f32_16x16x32_bf16(a0, b, acc[0][ct], 0, 0, 0);
      acc[1][ct] = __builtin_amdgcn_mfma_f32_16x16x32_bf16(a1, b, acc[1][ct], 0, 0, 0);
    }
  }
  // C/D layout: col = l&15, row = q*4 + reg
#pragma unroll
  for (int rt2 = 0; rt2 < 2; ++rt2){
    int nb = row0 + rt2 * 16 + q * 4;
#pragma unroll
    for (int ct = 0; ct < 16; ++ct){
#pragma unroll
      for (int r = 0; r < 4; ++r){
        int n = nb + r;
        if (n < n_nodes) hp[(size_t)n * C + ct * 16 + m15] = acc[rt2][ct][r];
      }
    }
  }
}

// ---------- attn_src[n,h], attn_trg[n,h] ----------
__global__ void attn_kernel(const float* __restrict__ hp,
                            const float* __restrict__ a_src,
                            const float* __restrict__ a_trg,
                            float* __restrict__ as_, float* __restrict__ at_,
                            int nh){
  int i = blockIdx.x * 256 + threadIdx.x;
  if (i >= nh) return;
  int n = i >> 3, h = i & 7;
  const float* row = hp + (size_t)n * C + h * O;
  const float* vs = a_src + h * O;
  const float* vt = a_trg + h * O;
  float s = 0.f, t = 0.f;
#pragma unroll
  for (int o = 0; o < O; ++o){
    float v = row[o];
    s = fmaf(v, vs[o], s);
    t = fmaf(v, vt[o], t);
  }
  as_[i] = s;
  at_[i] = t;
}

// ---------- global max, grid-stride + one atomic per block ----------
__global__ __launch_bounds__(256) void max_kernel(
    const float* __restrict__ as_, const float* __restrict__ at_,
    const int* __restrict__ src, const int* __restrict__ trg,
    unsigned* __restrict__ maxbuf, int eh){
  float v = -3.402823466e38f;
  for (int i = blockIdx.x * 256 + threadIdx.x; i < eh; i += gridDim.x * 256){
    int e = i >> 3, h = i & 7;
    float x = as_[src[e] * H + h] + at_[trg[e] * H + h];
    x = (x >= 0.f) ? x : NEG_SLOPE * x;
    v = fmaxf(v, x);
  }
  for (int off = 32; off > 0; off >>= 1)
    v = fmaxf(v, __shfl_down(v, off, 64));
  __shared__ float sm[4];
  int lane = threadIdx.x & 63, wv = threadIdx.x >> 6;
  if (lane == 0) sm[wv] = v;
  __syncthreads();
  if (threadIdx.x == 0){
    float m = fmaxf(fmaxf(sm[0], sm[1]), fmaxf(sm[2], sm[3]));
    atomicMax(maxbuf, enc_f(m));
  }
}

// ---------- exp_e ----------
__global__ void edge_kernel(const float* __restrict__ as_, const float* __restrict__ at_,
                            const int* __restrict__ src, const int* __restrict__ trg,
                            const unsigned* __restrict__ maxbuf,
                            float* __restrict__ expe, int eh){
  int i = blockIdx.x * 256 + threadIdx.x;
  if (i >= eh) return;
  int e = i >> 3, h = i & 7;
  float m = dec_f(*maxbuf);
  float x = as_[src[e] * H + h] + at_[trg[e] * H + h];
  x = (x >= 0.f) ? x : NEG_SLOPE * x;
  expe[i] = expf(x - m);
}

// ---------- CSR gather: one wave per destination node ----------
// MODE 0: elu(acc/denom) -> bf16 mfma-frag layout (layer-2 GEMM A-operand)
// MODE 1: head-mean -> emb[n,32] fp32
template<int MODE>
__global__ __launch_bounds__(256) void gather_kernel(
    const float* __restrict__ hp, const float* __restrict__ expe,
    const int* __restrict__ src, const int* __restrict__ row_ptr,
    const int* __restrict__ eidx, float* __restrict__ outf,
    short* __restrict__ outb, int n_nodes){
  int wid = (blockIdx.x * 256 + threadIdx.x) >> 6;
  if (wid >= n_nodes) return;
  int lane = threadIdx.x & 63;
  int head = lane >> 3;
  int beg = row_ptr[wid], end = row_ptr[wid + 1];
  float4 acc = {0.f, 0.f, 0.f, 0.f};
  float dsum = 0.f;
  for (int j = beg; j < end; ++j){
    int e = eidx[j];
    float ex = expe[e * H + head];
    int s = src[e];
    const float4 v = *(const float4*)(hp + (size_t)s * C + lane * 4);
    dsum += ex;
    acc.x = fmaf(v.x, ex, acc.x);
    acc.y = fmaf(v.y, ex, acc.y);
    acc.z = fmaf(v.z, ex, acc.z);
    acc.w = fmaf(v.w, ex, acc.w);
  }
  float inv = 1.f / (dsum + EPS_V);
  acc.x *= inv; acc.y *= inv; acc.z *= inv; acc.w *= inv;
  if (MODE == 0){
    float4 r;
    r.x = (acc.x > 0.f) ? acc.x : expm1f(acc.x);
    r.y = (acc.y > 0.f) ? acc.y : expm1f(acc.y);
    r.z = (acc.z > 0.f) ? acc.z : expm1f(acc.z);
    r.w = (acc.w > 0.f) ? acc.w : expm1f(acc.w);
    // write channels c=4*lane..4*lane+3 as frag elems: kb=lane>>1, j0=(lane&1)*4
    short4 s4;
    s4.x = (short)f2bf(r.x); s4.y = (short)f2bf(r.y);
    s4.z = (short)f2bf(r.z); s4.w = (short)f2bf(r.w);
    size_t off = (((size_t)(wid >> 4) * 32 + (lane >> 1)) * 16 + (wid & 15)) * 8
               + (lane & 1) * 4;
    *(short4*)(outb + off) = s4;
  } else {
#pragma unroll
    for (int mask = 8; mask <= 32; mask <<= 1){
      acc.x += __shfl_xor(acc.x, mask, 64);
      acc.y += __shfl_xor(acc.y, mask, 64);
      acc.z += __shfl_xor(acc.z, mask, 64);
      acc.w += __shfl_xor(acc.w, mask, 64);
    }
    if (lane < 8){
      float4 r;
      r.x = acc.x * 0.125f; r.y = acc.y * 0.125f;
      r.z = acc.z * 0.125f; r.w = acc.w * 0.125f;
      *(float4*)(outf + (size_t)wid * O + lane * 4) = r;
    }
  }
}

__global__ void final_kernel(const float* __restrict__ e0, const float* __restrict__ e1,
                             const float* __restrict__ fw, const float* __restrict__ fb,
                             float* __restrict__ out, int n_user){
  int n = blockIdx.x * 256 + threadIdx.x;
  if (n >= n_user) return;
  float l0 = fb[0], l1 = fb[1];
  const float* p0 = e0 + (size_t)n * O;
  const float* p1 = e1 + (size_t)n * O;
#pragma unroll
  for (int o = 0; o < O; ++o){
    float v = p0[o];
    l0 = fmaf(v, fw[o * 2 + 0], l0);
    l1 = fmaf(v, fw[o * 2 + 1], l1);
  }
#pragma unroll
  for (int o = 0; o < O; ++o){
    float v = p1[o];
    l0 = fmaf(v, fw[(O + o) * 2 + 0], l0);
    l1 = fmaf(v, fw[(O + o) * 2 + 1], l1);
  }
  float m = fmaxf(l0, l1);
  float lse = m + logf(expf(l0 - m) + expf(l1 - m));
  out[n * 2 + 0] = l0 - lse;
  out[n * 2 + 1] = l1 - lse;
}

extern "C" void kernel_launch(void* const* d_in, const int* in_sizes, int n_in,
                              void* d_out, int out_size, void* d_ws, size_t ws_size,
                              hipStream_t stream){
  const float* h0 = (const float*)d_in[0];
  const float* h1 = (const float*)d_in[1];
  const int* src0 = (const int*)d_in[2];
  const int* trg0 = (const int*)d_in[3];
  const int* src1 = (const int*)d_in[4];
  const int* trg1 = (const int*)d_in[5];
  const float* W [2][2] = {{(const float*)d_in[6],  (const float*)d_in[9]},
                           {(const float*)d_in[12], (const float*)d_in[15]}};
  const float* AS[2][2] = {{(const float*)d_in[7],  (const float*)d_in[10]},
                           {(const float*)d_in[13], (const float*)d_in[16]}};
  const float* AT[2][2] = {{(const float*)d_in[8],  (const float*)d_in[11]},
                           {(const float*)d_in[14], (const float*)d_in[17]}};
  const float* fc_w = (const float*)d_in[18];
  const float* fc_b = (const float*)d_in[19];
  float* out = (float*)d_out;

  const int N = in_sizes[0] / 128;   // 60000
  const int E = in_sizes[2];         // 800000
  const int n_user = out_size / 2;   // 50000

  const int RT = (N + 127) / 128 * 8;          // row tiles incl. 128-row block padding (3752)

  // workspace layout
  float* ws = (float*)d_ws;
  float* hp     = ws;  ws += (size_t)N * C;         // h_prime [N,256] fp32
  float* expe   = ws;  ws += (size_t)E * H;         // exp(e) [E,8]
  float* attn_s = ws;  ws += (size_t)N * H;
  float* attn_t = ws;  ws += (size_t)N * H;
  float* emb[2];
  emb[0] = ws;         ws += (size_t)n_user * O;
  emb[1] = ws;         ws += (size_t)n_user * O;
  short* hb = (short*)ws;  ws += (size_t)RT * 32 * 128 / 2;  // bf16 A frags (max F=256)
  short* wb = (short*)ws;  ws += (size_t)32 * 256 * 8 / 2;   // bf16 B frags (max F=256)
  int* row_ptr = (int*)ws;  ws += (size_t)(N + 1);
  int* eidx    = (int*)ws;  ws += (size_t)E;
  int* cursor  = (int*)ws;  ws += (size_t)N;
  unsigned* maxbuf = (unsigned*)ws;

  const float* hin [2] = {h0, h1};
  const int*   srcs[2] = {src0, src1};
  const int*   trgs[2] = {trg0, trg1};

  const int nh = N * H;
  const int eh = E * H;
  const int gemm_grid = (N + 127) / 128;

  for (int s = 0; s < 2; ++s){
    const int* src = srcs[s];
    const int* trg = trgs[s];

    // --- CSR build by trg (reused by both layers) ---
    hipMemsetAsync(cursor, 0, (size_t)N * sizeof(int), stream);
    count_kernel<<<(E + 255) / 256, 256, 0, stream>>>(trg, cursor, E);
    scan_kernel<<<1, 1024, 0, stream>>>(cursor, row_ptr, N);
    hipMemsetAsync(cursor, 0, (size_t)N * sizeof(int), stream);
    fill_kernel<<<(E + 255) / 256, 256, 0, stream>>>(trg, row_ptr, cursor, eidx, E);

    for (int l = 0; l < 2; ++l){
      // 1. GEMM (bf16 MFMA): h_prime = A @ W
      if (l == 0){
        int tot = RT * 16 * 16;   // rt * KB(16) * m(16)
        cvt_a_kernel<128><<<(tot + 255) / 256, 256, 0, stream>>>(hin[s], hb, N, tot);
        cvt_w_kernel<128><<<(256 * 16 + 255) / 256, 256, 0, stream>>>(W[s][0], wb);
        gemm_mfma<128><<<gemm_grid, 256, 0, stream>>>(hb, wb, hp, N);
      } else {
        // hb already written by gather_kernel<0> in frag layout (F=256)
        cvt_w_kernel<256><<<(256 * 32 + 255) / 256, 256, 0, stream>>>(W[s][1], wb);
        gemm_mfma<256><<<gemm_grid, 256, 0, stream>>>(hb, wb, hp, N);
      }
      // 2. per-node attention logits
      attn_kernel<<<(nh + 255) / 256, 256, 0, stream>>>(hp, AS[s][l], AT[s][l],
                                                        attn_s, attn_t, nh);
      // 3. global max (reference's max-shift)
      init_max_kernel<<<1, 1, 0, stream>>>(maxbuf);
      max_kernel<<<1024, 256, 0, stream>>>(attn_s, attn_t, src, trg, maxbuf, eh);
      // 4. exp(e)
      edge_kernel<<<(eh + 255) / 256, 256, 0, stream>>>(attn_s, attn_t, src, trg,
                                                        maxbuf, expe, eh);
      // 5. CSR gather (fused normalize + epilogue)
      if (l == 0)
        gather_kernel<0><<<(N * 64 + 255) / 256, 256, 0, stream>>>(
            hp, expe, src, row_ptr, eidx, nullptr, hb, N);
      else
        gather_kernel<1><<<(n_user * 64 + 255) / 256, 256, 0, stream>>>(
            hp, expe, src, row_ptr, eidx, emb[s], nullptr, n_user);
    }
  }

  final_kernel<<<(n_user + 255) / 256, 256, 0, stream>>>(emb[0], emb[1], fc_w, fc_b,
                                                         out, n_user);
}

// Round 5
// 1237.682 us; speedup vs baseline: 3.8358x; 1.2097x over previous
//
#include <hip/hip_runtime.h>
#include <math.h>

#define H 8
#define O 32
#define C 256            // H*O
#define NEG_SLOPE 0.2f
#define EPS_V 1e-16f

typedef float f32x4 __attribute__((ext_vector_type(4)));
typedef short bf16x8 __attribute__((ext_vector_type(8)));

__device__ __forceinline__ unsigned short f2bf(float x){
  unsigned u = __float_as_uint(x);
  unsigned r = (u + 0x7fffu + ((u >> 16) & 1u)) >> 16;   // RNE
  return (unsigned short)r;
}
__device__ __forceinline__ float bf2f(unsigned short u){
  return __uint_as_float((unsigned)u << 16);
}

// ---------- CSR build ----------
__global__ void count_kernel(const int* __restrict__ trg, int* __restrict__ deg, int E){
  int e = blockIdx.x * 256 + threadIdx.x;
  if (e < E) atomicAdd(&deg[trg[e]], 1);
}

__global__ void scan_kernel(const int* __restrict__ deg, int* __restrict__ row_ptr, int n){
  __shared__ int sm[1024];
  int run = 0;
  if (threadIdx.x == 0) row_ptr[0] = 0;
  for (int base = 0; base < n; base += 1024){
    int i = base + threadIdx.x;
    int v = (i < n) ? deg[i] : 0;
    sm[threadIdx.x] = v;
    __syncthreads();
    for (int off = 1; off < 1024; off <<= 1){
      int t = (threadIdx.x >= off) ? sm[threadIdx.x - off] : 0;
      __syncthreads();
      sm[threadIdx.x] += t;
      __syncthreads();
    }
    if (i < n) row_ptr[i + 1] = run + sm[threadIdx.x];
    run += sm[1023];
    __syncthreads();
  }
}

__global__ void fill_kernel(const int* __restrict__ trg, const int* __restrict__ row_ptr,
                            int* __restrict__ cursor, int* __restrict__ eidx, int E){
  int e = blockIdx.x * 256 + threadIdx.x;
  if (e >= E) return;
  int t = trg[e];
  int p = atomicAdd(&cursor[t], 1);
  eidx[row_ptr[t] + p] = e;
}

// ---------- A-operand conversion: fp32 [N,F] row-major -> bf16 mfma-frag layout ----------
template<int F>
__global__ void cvt_a_kernel(const float* __restrict__ src, short* __restrict__ dst,
                             int n_nodes, int total){
  constexpr int KB = F / 8;
  int t = blockIdx.x * 256 + threadIdx.x;
  if (t >= total) return;
  int kb = t % KB;
  int m  = (t / KB) & 15;
  int rt = t / (KB * 16);
  int row = rt * 16 + m;
  float v[8];
  if (row < n_nodes){
    const float4 p0 = *(const float4*)(src + (size_t)row * F + kb * 8);
    const float4 p1 = *(const float4*)(src + (size_t)row * F + kb * 8 + 4);
    v[0]=p0.x; v[1]=p0.y; v[2]=p0.z; v[3]=p0.w;
    v[4]=p1.x; v[5]=p1.y; v[6]=p1.z; v[7]=p1.w;
  } else {
    for (int j = 0; j < 8; ++j) v[j] = 0.f;
  }
  bf16x8 o;
  for (int j = 0; j < 8; ++j) o[j] = (short)f2bf(v[j]);
  *(bf16x8*)(dst + (((size_t)rt * KB + kb) * 16 + m) * 8) = o;
}

// ---------- B-operand conversion: w[h][f][o] fp32 -> bf16 frag layout ----------
template<int F>
__global__ void cvt_w_kernel(const float* __restrict__ w, short* __restrict__ wb){
  constexpr int KB = F / 8;
  int t = blockIdx.x * 256 + threadIdx.x;
  if (t >= 256 * KB) return;
  int c = t & 255, kb = t >> 8;
  int h = c >> 5, o = c & 31;
  bf16x8 out;
  for (int j = 0; j < 8; ++j){
    int f = kb * 8 + j;
    out[j] = (short)f2bf(w[((size_t)h * F + f) * O + o]);
  }
  *(bf16x8*)(wb + ((size_t)kb * 256 + c) * 8) = out;
}

// ---------- MFMA GEMM: hp[N,256](bf16) = A[N,F] @ W[F,256] ----------
template<int F>
__global__ __launch_bounds__(256) void gemm_mfma(
    const short* __restrict__ hb, const short* __restrict__ wb,
    unsigned short* __restrict__ hp, int n_nodes){
  constexpr int KB = F / 8;
  const int w = threadIdx.x >> 6, l = threadIdx.x & 63;
  const int q = l >> 4, m15 = l & 15;
  const int row0 = blockIdx.x * 128 + w * 32;
  const size_t rt0 = row0 >> 4;
  f32x4 acc[2][16] = {};
  for (int kk = 0; kk < F / 32; ++kk){
    const int kb0 = kk * 4 + q;
    bf16x8 a0 = *(const bf16x8*)(hb + ((rt0 * KB + kb0) * 16 + m15) * 8);
    bf16x8 a1 = *(const bf16x8*)(hb + (((rt0 + 1) * KB + kb0) * 16 + m15) * 8);
    const short* wp = wb + ((size_t)kb0 * 256 + m15) * 8;
#pragma unroll
    for (int ct = 0; ct < 16; ++ct){
      bf16x8 b = *(const bf16x8*)(wp + ct * 128);
      acc[0][ct] = __builtin_amdgcn_mfma_f32_16x16x32_bf16(a0, b, acc[0][ct], 0, 0, 0);
      acc[1][ct] = __builtin_amdgcn_mfma_f32_16x16x32_bf16(a1, b, acc[1][ct], 0, 0, 0);
    }
  }
  // C/D layout: col = l&15, row = q*4 + reg
#pragma unroll
  for (int rt2 = 0; rt2 < 2; ++rt2){
    int nb = row0 + rt2 * 16 + q * 4;
#pragma unroll
    for (int ct = 0; ct < 16; ++ct){
#pragma unroll
      for (int r = 0; r < 4; ++r){
        int n = nb + r;
        if (n < n_nodes) hp[(size_t)n * C + ct * 16 + m15] = f2bf(acc[rt2][ct][r]);
      }
    }
  }
}

// ---------- attn_src[n,h], attn_trg[n,h] from bf16 hp ----------
__global__ void attn_kernel(const unsigned short* __restrict__ hp,
                            const float* __restrict__ a_src,
                            const float* __restrict__ a_trg,
                            float* __restrict__ as_, float* __restrict__ at_,
                            int nh){
  int i = blockIdx.x * 256 + threadIdx.x;
  if (i >= nh) return;
  int n = i >> 3, h = i & 7;
  const uint4* row = (const uint4*)(hp + (size_t)n * C + h * O);
  const float* vs = a_src + h * O;
  const float* vt = a_trg + h * O;
  float s = 0.f, t = 0.f;
#pragma unroll
  for (int v4 = 0; v4 < 4; ++v4){
    uint4 p = row[v4];
    unsigned arr[4] = {p.x, p.y, p.z, p.w};
#pragma unroll
    for (int k = 0; k < 4; ++k){
      float lo = __uint_as_float(arr[k] << 16);
      float hi = __uint_as_float(arr[k] & 0xffff0000u);
      int o = v4 * 8 + k * 2;
      s = fmaf(lo, vs[o], s); s = fmaf(hi, vs[o + 1], s);
      t = fmaf(lo, vt[o], t); t = fmaf(hi, vt[o + 1], t);
    }
  }
  as_[i] = s;
  at_[i] = t;
}

// ---------- fused CSR gather: softmax weights computed on the fly ----------
// (global max-shift dropped: exp(x-m)/sum exp(x-m) == exp(x)/sum exp(x);
//  the shift only enters via EPS=1e-16, negligible at these logit scales)
// one wave per destination node; lane handles channels 4*lane..4*lane+3
// MODE 0: elu -> bf16 mfma-frag layout (layer-2 A-operand)
// MODE 1: head-mean -> emb[n,32] fp32
template<int MODE>
__global__ __launch_bounds__(256) void gather_kernel(
    const unsigned short* __restrict__ hp,
    const float* __restrict__ as_, const float* __restrict__ at_,
    const int* __restrict__ src, const int* __restrict__ row_ptr,
    const int* __restrict__ eidx, float* __restrict__ outf,
    short* __restrict__ outb, int n_nodes){
  int wid = (blockIdx.x * 256 + threadIdx.x) >> 6;
  if (wid >= n_nodes) return;
  int lane = threadIdx.x & 63;
  int head = lane >> 3;
  float ath = at_[wid * H + head];
  int beg = row_ptr[wid], end = row_ptr[wid + 1];
  float4 acc = {0.f, 0.f, 0.f, 0.f};
  float dsum = 0.f;
  for (int j = beg; j < end; ++j){
    int e = eidx[j];
    int s = src[e];
    float x = as_[s * H + head] + ath;
    x = (x >= 0.f) ? x : NEG_SLOPE * x;
    float ex = expf(x);
    const ushort4 v = *(const ushort4*)(hp + (size_t)s * C + lane * 4);
    dsum += ex;
    acc.x = fmaf(bf2f(v.x), ex, acc.x);
    acc.y = fmaf(bf2f(v.y), ex, acc.y);
    acc.z = fmaf(bf2f(v.z), ex, acc.z);
    acc.w = fmaf(bf2f(v.w), ex, acc.w);
  }
  float inv = 1.f / (dsum + EPS_V);
  acc.x *= inv; acc.y *= inv; acc.z *= inv; acc.w *= inv;
  if (MODE == 0){
    float4 r;
    r.x = (acc.x > 0.f) ? acc.x : expm1f(acc.x);
    r.y = (acc.y > 0.f) ? acc.y : expm1f(acc.y);
    r.z = (acc.z > 0.f) ? acc.z : expm1f(acc.z);
    r.w = (acc.w > 0.f) ? acc.w : expm1f(acc.w);
    short4 s4;
    s4.x = (short)f2bf(r.x); s4.y = (short)f2bf(r.y);
    s4.z = (short)f2bf(r.z); s4.w = (short)f2bf(r.w);
    size_t off = (((size_t)(wid >> 4) * 32 + (lane >> 1)) * 16 + (wid & 15)) * 8
               + (lane & 1) * 4;
    *(short4*)(outb + off) = s4;
  } else {
#pragma unroll
    for (int mask = 8; mask <= 32; mask <<= 1){
      acc.x += __shfl_xor(acc.x, mask, 64);
      acc.y += __shfl_xor(acc.y, mask, 64);
      acc.z += __shfl_xor(acc.z, mask, 64);
      acc.w += __shfl_xor(acc.w, mask, 64);
    }
    if (lane < 8){
      float4 r;
      r.x = acc.x * 0.125f; r.y = acc.y * 0.125f;
      r.z = acc.z * 0.125f; r.w = acc.w * 0.125f;
      *(float4*)(outf + (size_t)wid * O + lane * 4) = r;
    }
  }
}

__global__ void final_kernel(const float* __restrict__ e0, const float* __restrict__ e1,
                             const float* __restrict__ fw, const float* __restrict__ fb,
                             float* __restrict__ out, int n_user){
  int n = blockIdx.x * 256 + threadIdx.x;
  if (n >= n_user) return;
  float l0 = fb[0], l1 = fb[1];
  const float* p0 = e0 + (size_t)n * O;
  const float* p1 = e1 + (size_t)n * O;
#pragma unroll
  for (int o = 0; o < O; ++o){
    float v = p0[o];
    l0 = fmaf(v, fw[o * 2 + 0], l0);
    l1 = fmaf(v, fw[o * 2 + 1], l1);
  }
#pragma unroll
  for (int o = 0; o < O; ++o){
    float v = p1[o];
    l0 = fmaf(v, fw[(O + o) * 2 + 0], l0);
    l1 = fmaf(v, fw[(O + o) * 2 + 1], l1);
  }
  float m = fmaxf(l0, l1);
  float lse = m + logf(expf(l0 - m) + expf(l1 - m));
  out[n * 2 + 0] = l0 - lse;
  out[n * 2 + 1] = l1 - lse;
}

extern "C" void kernel_launch(void* const* d_in, const int* in_sizes, int n_in,
                              void* d_out, int out_size, void* d_ws, size_t ws_size,
                              hipStream_t stream){
  const float* h0 = (const float*)d_in[0];
  const float* h1 = (const float*)d_in[1];
  const int* src0 = (const int*)d_in[2];
  const int* trg0 = (const int*)d_in[3];
  const int* src1 = (const int*)d_in[4];
  const int* trg1 = (const int*)d_in[5];
  const float* W [2][2] = {{(const float*)d_in[6],  (const float*)d_in[9]},
                           {(const float*)d_in[12], (const float*)d_in[15]}};
  const float* AS[2][2] = {{(const float*)d_in[7],  (const float*)d_in[10]},
                           {(const float*)d_in[13], (const float*)d_in[16]}};
  const float* AT[2][2] = {{(const float*)d_in[8],  (const float*)d_in[11]},
                           {(const float*)d_in[14], (const float*)d_in[17]}};
  const float* fc_w = (const float*)d_in[18];
  const float* fc_b = (const float*)d_in[19];
  float* out = (float*)d_out;

  const int N = in_sizes[0] / 128;   // 60000
  const int E = in_sizes[2];         // 800000
  const int n_user = out_size / 2;   // 50000

  const int RT = (N + 127) / 128 * 8;   // 16-row tiles incl. 128-row padding

  // workspace layout
  float* ws = (float*)d_ws;
  float* attn_s = ws;  ws += (size_t)N * H;
  float* attn_t = ws;  ws += (size_t)N * H;
  float* emb[2];
  emb[0] = ws;         ws += (size_t)n_user * O;
  emb[1] = ws;         ws += (size_t)n_user * O;
  unsigned short* hp = (unsigned short*)ws;  ws += (size_t)N * C / 2;   // bf16 h_prime
  short* hb = (short*)ws;  ws += (size_t)RT * 32 * 128 / 2;  // bf16 A frags (max F=256)
  short* wb = (short*)ws;  ws += (size_t)32 * 256 * 8 / 2;   // bf16 B frags (max F=256)
  int* row_ptr = (int*)ws;  ws += (size_t)(N + 1);
  int* eidx    = (int*)ws;  ws += (size_t)E;
  int* cursor  = (int*)ws;  ws += (size_t)N;

  const float* hin [2] = {h0, h1};
  const int*   srcs[2] = {src0, src1};
  const int*   trgs[2] = {trg0, trg1};

  const int nh = N * H;
  const int gemm_grid = (N + 127) / 128;

  for (int s = 0; s < 2; ++s){
    const int* src = srcs[s];
    const int* trg = trgs[s];

    // --- CSR build by trg (reused by both layers) ---
    hipMemsetAsync(cursor, 0, (size_t)N * sizeof(int), stream);
    count_kernel<<<(E + 255) / 256, 256, 0, stream>>>(trg, cursor, E);
    scan_kernel<<<1, 1024, 0, stream>>>(cursor, row_ptr, N);
    hipMemsetAsync(cursor, 0, (size_t)N * sizeof(int), stream);
    fill_kernel<<<(E + 255) / 256, 256, 0, stream>>>(trg, row_ptr, cursor, eidx, E);

    for (int l = 0; l < 2; ++l){
      // 1. GEMM (bf16 MFMA): h_prime = A @ W
      if (l == 0){
        int tot = RT * 16 * 16;
        cvt_a_kernel<128><<<(tot + 255) / 256, 256, 0, stream>>>(hin[s], hb, N, tot);
        cvt_w_kernel<128><<<(256 * 16 + 255) / 256, 256, 0, stream>>>(W[s][0], wb);
        gemm_mfma<128><<<gemm_grid, 256, 0, stream>>>(hb, wb, hp, N);
      } else {
        // hb already written by gather_kernel<0> in frag layout (F=256)
        cvt_w_kernel<256><<<(256 * 32 + 255) / 256, 256, 0, stream>>>(W[s][1], wb);
        gemm_mfma<256><<<gemm_grid, 256, 0, stream>>>(hb, wb, hp, N);
      }
      // 2. per-node attention logits
      attn_kernel<<<(nh + 255) / 256, 256, 0, stream>>>(hp, AS[s][l], AT[s][l],
                                                        attn_s, attn_t, nh);
      // 3. fused softmax + CSR gather + epilogue
      if (l == 0)
        gather_kernel<0><<<(N * 64 + 255) / 256, 256, 0, stream>>>(
            hp, attn_s, attn_t, src, row_ptr, eidx, nullptr, hb, N);
      else
        gather_kernel<1><<<(n_user * 64 + 255) / 256, 256, 0, stream>>>(
            hp, attn_s, attn_t, src, row_ptr, eidx, emb[s], nullptr, n_user);
    }
  }

  final_kernel<<<(n_user + 255) / 256, 256, 0, stream>>>(emb[0], emb[1], fc_w, fc_b,
                                                         out, n_user);
}

// Round 6
// 765.771 us; speedup vs baseline: 6.1996x; 1.6163x over previous
//
#include <hip/hip_runtime.h>
#include <math.h>

#define H 8
#define O 32
#define C 256            // H*O
#define NEG_SLOPE 0.2f
#define EPS_V 1e-16f

typedef float f32x4 __attribute__((ext_vector_type(4)));
typedef short bf16x8 __attribute__((ext_vector_type(8)));

__device__ __forceinline__ unsigned short f2bf(float x){
  unsigned u = __float_as_uint(x);
  unsigned r = (u + 0x7fffu + ((u >> 16) & 1u)) >> 16;   // RNE
  return (unsigned short)r;
}

// ---------- CSR build ----------
__global__ void count_kernel(const int* __restrict__ trg, int* __restrict__ deg, int E){
  int e = blockIdx.x * 256 + threadIdx.x;
  if (e < E) atomicAdd(&deg[trg[e]], 1);
}

// 3-kernel scan (replaces 59-iteration single-block scan)
__global__ void scan_block_kernel(const int* __restrict__ deg, int* __restrict__ row_ptr,
                                  int* __restrict__ bsum, int n){
  __shared__ int sm[1024];
  int i = blockIdx.x * 1024 + threadIdx.x;
  int v = (i < n) ? deg[i] : 0;
  sm[threadIdx.x] = v;
  __syncthreads();
  for (int off = 1; off < 1024; off <<= 1){
    int t = (threadIdx.x >= off) ? sm[threadIdx.x - off] : 0;
    __syncthreads();
    sm[threadIdx.x] += t;
    __syncthreads();
  }
  if (i < n) row_ptr[i + 1] = sm[threadIdx.x];
  if (threadIdx.x == 1023) bsum[blockIdx.x] = sm[1023];
  if (i == 0) row_ptr[0] = 0;
}

__global__ void scan_top_kernel(int* __restrict__ bsum, int nb){
  __shared__ int sm[256];
  int t = threadIdx.x;
  int v = (t < nb) ? bsum[t] : 0;
  sm[t] = v;
  __syncthreads();
  for (int off = 1; off < 256; off <<= 1){
    int x = (t >= off) ? sm[t - off] : 0;
    __syncthreads();
    sm[t] += x;
    __syncthreads();
  }
  if (t < nb) bsum[t] = (t == 0) ? 0 : sm[t - 1];
}

__global__ void scan_add_kernel(int* __restrict__ row_ptr, const int* __restrict__ bsum, int n){
  int i = blockIdx.x * 256 + threadIdx.x;
  if (i < n) row_ptr[i + 1] += bsum[i >> 10];
}

// fill: write src[e] directly in CSR order (drops eidx indirection in gather)
__global__ void fill_kernel(const int* __restrict__ trg, const int* __restrict__ src,
                            const int* __restrict__ row_ptr,
                            int* __restrict__ cursor, int* __restrict__ csrc, int E){
  int e = blockIdx.x * 256 + threadIdx.x;
  if (e >= E) return;
  int t = trg[e];
  int p = atomicAdd(&cursor[t], 1);
  csrc[row_ptr[t] + p] = src[e];
}

// ---------- A-operand conversion: fp32 [N,F] row-major -> bf16 mfma-frag layout ----------
template<int F>
__global__ void cvt_a_kernel(const float* __restrict__ src, short* __restrict__ dst,
                             int n_nodes, int total){
  constexpr int KB = F / 8;
  int t = blockIdx.x * 256 + threadIdx.x;
  if (t >= total) return;
  int kb = t % KB;
  int m  = (t / KB) & 15;
  int rt = t / (KB * 16);
  int row = rt * 16 + m;
  float v[8];
  if (row < n_nodes){
    const float4 p0 = *(const float4*)(src + (size_t)row * F + kb * 8);
    const float4 p1 = *(const float4*)(src + (size_t)row * F + kb * 8 + 4);
    v[0]=p0.x; v[1]=p0.y; v[2]=p0.z; v[3]=p0.w;
    v[4]=p1.x; v[5]=p1.y; v[6]=p1.z; v[7]=p1.w;
  } else {
    for (int j = 0; j < 8; ++j) v[j] = 0.f;
  }
  bf16x8 o;
  for (int j = 0; j < 8; ++j) o[j] = (short)f2bf(v[j]);
  *(bf16x8*)(dst + (((size_t)rt * KB + kb) * 16 + m) * 8) = o;
}

// ---------- B-operand conversion: w[h][f][o] fp32 -> bf16 frag layout ----------
template<int F>
__global__ void cvt_w_kernel(const float* __restrict__ w, short* __restrict__ wb){
  constexpr int KB = F / 8;
  int t = blockIdx.x * 256 + threadIdx.x;
  if (t >= 256 * KB) return;
  int c = t & 255, kb = t >> 8;
  int h = c >> 5, o = c & 31;
  bf16x8 out;
  for (int j = 0; j < 8; ++j){
    int f = kb * 8 + j;
    out[j] = (short)f2bf(w[((size_t)h * F + f) * O + o]);
  }
  *(bf16x8*)(wb + ((size_t)kb * 256 + c) * 8) = out;
}

// ---------- MFMA GEMM: hp[N,256](bf16) = A[N,F] @ W[F,256] ----------
template<int F>
__global__ __launch_bounds__(256) void gemm_mfma(
    const short* __restrict__ hb, const short* __restrict__ wb,
    unsigned short* __restrict__ hp, int n_nodes){
  constexpr int KB = F / 8;
  const int w = threadIdx.x >> 6, l = threadIdx.x & 63;
  const int q = l >> 4, m15 = l & 15;
  const int row0 = blockIdx.x * 128 + w * 32;
  const size_t rt0 = row0 >> 4;
  f32x4 acc[2][16] = {};
  for (int kk = 0; kk < F / 32; ++kk){
    const int kb0 = kk * 4 + q;
    bf16x8 a0 = *(const bf16x8*)(hb + ((rt0 * KB + kb0) * 16 + m15) * 8);
    bf16x8 a1 = *(const bf16x8*)(hb + (((rt0 + 1) * KB + kb0) * 16 + m15) * 8);
    const short* wp = wb + ((size_t)kb0 * 256 + m15) * 8;
#pragma unroll
    for (int ct = 0; ct < 16; ++ct){
      bf16x8 b = *(const bf16x8*)(wp + ct * 128);
      acc[0][ct] = __builtin_amdgcn_mfma_f32_16x16x32_bf16(a0, b, acc[0][ct], 0, 0, 0);
      acc[1][ct] = __builtin_amdgcn_mfma_f32_16x16x32_bf16(a1, b, acc[1][ct], 0, 0, 0);
    }
  }
  // C/D layout: col = l&15, row = q*4 + reg
#pragma unroll
  for (int rt2 = 0; rt2 < 2; ++rt2){
    int nb = row0 + rt2 * 16 + q * 4;
#pragma unroll
    for (int ct = 0; ct < 16; ++ct){
#pragma unroll
      for (int r = 0; r < 4; ++r){
        int n = nb + r;
        if (n < n_nodes) hp[(size_t)n * C + ct * 16 + m15] = f2bf(acc[rt2][ct][r]);
      }
    }
  }
}

// ---------- attn_src[n,h], attn_trg[n,h] from bf16 hp ----------
__global__ void attn_kernel(const unsigned short* __restrict__ hp,
                            const float* __restrict__ a_src,
                            const float* __restrict__ a_trg,
                            float* __restrict__ as_, float* __restrict__ at_,
                            int nh){
  int i = blockIdx.x * 256 + threadIdx.x;
  if (i >= nh) return;
  int n = i >> 3, h = i & 7;
  const uint4* row = (const uint4*)(hp + (size_t)n * C + h * O);
  const float* vs = a_src + h * O;
  const float* vt = a_trg + h * O;
  float s = 0.f, t = 0.f;
#pragma unroll
  for (int v4 = 0; v4 < 4; ++v4){
    uint4 p = row[v4];
    unsigned arr[4] = {p.x, p.y, p.z, p.w};
#pragma unroll
    for (int k = 0; k < 4; ++k){
      float lo = __uint_as_float(arr[k] << 16);
      float hi = __uint_as_float(arr[k] & 0xffff0000u);
      int o = v4 * 8 + k * 2;
      s = fmaf(lo, vs[o], s); s = fmaf(hi, vs[o + 1], s);
      t = fmaf(lo, vt[o], t); t = fmaf(hi, vt[o + 1], t);
    }
  }
  as_[i] = s;
  at_[i] = t;
}

// ---------- fused CSR gather: half-wave per edge, 16B/lane ----------
// wave per node; lanes split: half = lane>>5 handles edges j = beg+half, +2, ...
// l = lane&31 covers channels 8l..8l+7 (head = l>>2); manual unroll x2 (4 edges in flight)
// MODE 0: elu -> bf16 mfma-frag layout (layer-2 A-operand)
// MODE 1: head-mean -> emb[n,32] fp32
template<int MODE>
__global__ __launch_bounds__(256) void gather_kernel(
    const unsigned short* __restrict__ hp,
    const float* __restrict__ as_, const float* __restrict__ at_,
    const int* __restrict__ csrc, const int* __restrict__ row_ptr,
    float* __restrict__ outf, short* __restrict__ outb, int n_nodes){
  int wid = (blockIdx.x * 256 + threadIdx.x) >> 6;
  if (wid >= n_nodes) return;
  int lane = threadIdx.x & 63;
  int half = lane >> 5;
  int l = lane & 31;
  int head = l >> 2;
  float ath = at_[wid * H + head];
  int beg = row_ptr[wid], end = row_ptr[wid + 1];
  float acc[8] = {0.f,0.f,0.f,0.f,0.f,0.f,0.f,0.f};
  float dsum = 0.f;
  int j = beg + half;
  for (; j + 2 < end; j += 4){
    int s0 = csrc[j], s1 = csrc[j + 2];
    float x0 = as_[s0 * H + head] + ath;
    float x1 = as_[s1 * H + head] + ath;
    x0 = (x0 >= 0.f) ? x0 : NEG_SLOPE * x0;
    x1 = (x1 >= 0.f) ? x1 : NEG_SLOPE * x1;
    float e0 = expf(x0), e1 = expf(x1);
    const uint4 v0 = *(const uint4*)(hp + (size_t)s0 * C + l * 8);
    const uint4 v1 = *(const uint4*)(hp + (size_t)s1 * C + l * 8);
    dsum += e0 + e1;
    unsigned a0[4] = {v0.x, v0.y, v0.z, v0.w};
    unsigned a1[4] = {v1.x, v1.y, v1.z, v1.w};
#pragma unroll
    for (int k = 0; k < 4; ++k){
      acc[2*k]   = fmaf(__uint_as_float(a0[k] << 16),        e0, acc[2*k]);
      acc[2*k+1] = fmaf(__uint_as_float(a0[k] & 0xffff0000u), e0, acc[2*k+1]);
      acc[2*k]   = fmaf(__uint_as_float(a1[k] << 16),        e1, acc[2*k]);
      acc[2*k+1] = fmaf(__uint_as_float(a1[k] & 0xffff0000u), e1, acc[2*k+1]);
    }
  }
  if (j < end){
    int s0 = csrc[j];
    float x0 = as_[s0 * H + head] + ath;
    x0 = (x0 >= 0.f) ? x0 : NEG_SLOPE * x0;
    float e0 = expf(x0);
    const uint4 v0 = *(const uint4*)(hp + (size_t)s0 * C + l * 8);
    dsum += e0;
    unsigned a0[4] = {v0.x, v0.y, v0.z, v0.w};
#pragma unroll
    for (int k = 0; k < 4; ++k){
      acc[2*k]   = fmaf(__uint_as_float(a0[k] << 16),        e0, acc[2*k]);
      acc[2*k+1] = fmaf(__uint_as_float(a0[k] & 0xffff0000u), e0, acc[2*k+1]);
    }
  }
  // combine halves
  dsum += __shfl_xor(dsum, 32, 64);
#pragma unroll
  for (int k = 0; k < 8; ++k) acc[k] += __shfl_xor(acc[k], 32, 64);
  float inv = 1.f / (dsum + EPS_V);
#pragma unroll
  for (int k = 0; k < 8; ++k) acc[k] *= inv;
  if (MODE == 0){
    if (half == 0){
      bf16x8 o;
#pragma unroll
      for (int k = 0; k < 8; ++k){
        float r = (acc[k] > 0.f) ? acc[k] : expm1f(acc[k]);
        o[k] = (short)f2bf(r);
      }
      // frag layout: channel c=8l+k -> kb=l, j=k; m=wid&15, rt=wid>>4, KB=32
      *(bf16x8*)(outb + (((size_t)(wid >> 4) * 32 + l) * 16 + (wid & 15)) * 8) = o;
    }
  } else {
    // mean over heads: head index lives in bits 2..4 of l
#pragma unroll
    for (int mask = 4; mask <= 16; mask <<= 1){
#pragma unroll
      for (int k = 0; k < 8; ++k) acc[k] += __shfl_xor(acc[k], mask, 64);
    }
    if (half == 0 && l < 4){
      float4 r0 = {acc[0]*0.125f, acc[1]*0.125f, acc[2]*0.125f, acc[3]*0.125f};
      float4 r1 = {acc[4]*0.125f, acc[5]*0.125f, acc[6]*0.125f, acc[7]*0.125f};
      *(float4*)(outf + (size_t)wid * O + l * 8)     = r0;
      *(float4*)(outf + (size_t)wid * O + l * 8 + 4) = r1;
    }
  }
}

__global__ void final_kernel(const float* __restrict__ e0, const float* __restrict__ e1,
                             const float* __restrict__ fw, const float* __restrict__ fb,
                             float* __restrict__ out, int n_user){
  int n = blockIdx.x * 256 + threadIdx.x;
  if (n >= n_user) return;
  float l0 = fb[0], l1 = fb[1];
  const float* p0 = e0 + (size_t)n * O;
  const float* p1 = e1 + (size_t)n * O;
#pragma unroll
  for (int o = 0; o < O; ++o){
    float v = p0[o];
    l0 = fmaf(v, fw[o * 2 + 0], l0);
    l1 = fmaf(v, fw[o * 2 + 1], l1);
  }
#pragma unroll
  for (int o = 0; o < O; ++o){
    float v = p1[o];
    l0 = fmaf(v, fw[(O + o) * 2 + 0], l0);
    l1 = fmaf(v, fw[(O + o) * 2 + 1], l1);
  }
  float m = fmaxf(l0, l1);
  float lse = m + logf(expf(l0 - m) + expf(l1 - m));
  out[n * 2 + 0] = l0 - lse;
  out[n * 2 + 1] = l1 - lse;
}

extern "C" void kernel_launch(void* const* d_in, const int* in_sizes, int n_in,
                              void* d_out, int out_size, void* d_ws, size_t ws_size,
                              hipStream_t stream){
  const float* h0 = (const float*)d_in[0];
  const float* h1 = (const float*)d_in[1];
  const int* src0 = (const int*)d_in[2];
  const int* trg0 = (const int*)d_in[3];
  const int* src1 = (const int*)d_in[4];
  const int* trg1 = (const int*)d_in[5];
  const float* W [2][2] = {{(const float*)d_in[6],  (const float*)d_in[9]},
                           {(const float*)d_in[12], (const float*)d_in[15]}};
  const float* AS[2][2] = {{(const float*)d_in[7],  (const float*)d_in[10]},
                           {(const float*)d_in[13], (const float*)d_in[16]}};
  const float* AT[2][2] = {{(const float*)d_in[8],  (const float*)d_in[11]},
                           {(const float*)d_in[14], (const float*)d_in[17]}};
  const float* fc_w = (const float*)d_in[18];
  const float* fc_b = (const float*)d_in[19];
  float* out = (float*)d_out;

  const int N = in_sizes[0] / 128;   // 60000
  const int E = in_sizes[2];         // 800000
  const int n_user = out_size / 2;   // 50000

  const int RT = (N + 127) / 128 * 8;   // 16-row tiles incl. 128-row padding
  const int NB = (N + 1023) / 1024;     // scan blocks (59)

  // workspace layout
  float* ws = (float*)d_ws;
  float* attn_s = ws;  ws += (size_t)N * H;
  float* attn_t = ws;  ws += (size_t)N * H;
  float* emb[2];
  emb[0] = ws;         ws += (size_t)n_user * O;
  emb[1] = ws;         ws += (size_t)n_user * O;
  unsigned short* hp = (unsigned short*)ws;  ws += (size_t)N * C / 2;   // bf16 h_prime
  short* hb = (short*)ws;  ws += (size_t)RT * 32 * 128 / 2;  // bf16 A frags (max F=256)
  short* wb = (short*)ws;  ws += (size_t)32 * 256 * 8 / 2;   // bf16 B frags (max F=256)
  int* row_ptr = (int*)ws;  ws += (size_t)(N + 1);
  int* csrc    = (int*)ws;  ws += (size_t)E;
  int* cursor  = (int*)ws;  ws += (size_t)N;
  int* bsum    = (int*)ws;  ws += 256;

  const float* hin [2] = {h0, h1};
  const int*   srcs[2] = {src0, src1};
  const int*   trgs[2] = {trg0, trg1};

  const int nh = N * H;
  const int gemm_grid = (N + 127) / 128;

  for (int s = 0; s < 2; ++s){
    const int* src = srcs[s];
    const int* trg = trgs[s];

    // --- CSR build by trg (reused by both layers) ---
    hipMemsetAsync(cursor, 0, (size_t)N * sizeof(int), stream);
    count_kernel<<<(E + 255) / 256, 256, 0, stream>>>(trg, cursor, E);
    scan_block_kernel<<<NB, 1024, 0, stream>>>(cursor, row_ptr, bsum, N);
    scan_top_kernel<<<1, 256, 0, stream>>>(bsum, NB);
    scan_add_kernel<<<(N + 255) / 256, 256, 0, stream>>>(row_ptr, bsum, N);
    hipMemsetAsync(cursor, 0, (size_t)N * sizeof(int), stream);
    fill_kernel<<<(E + 255) / 256, 256, 0, stream>>>(trg, src, row_ptr, cursor, csrc, E);

    for (int l = 0; l < 2; ++l){
      // 1. GEMM (bf16 MFMA): h_prime = A @ W
      if (l == 0){
        int tot = RT * 16 * 16;
        cvt_a_kernel<128><<<(tot + 255) / 256, 256, 0, stream>>>(hin[s], hb, N, tot);
        cvt_w_kernel<128><<<(256 * 16 + 255) / 256, 256, 0, stream>>>(W[s][0], wb);
        gemm_mfma<128><<<gemm_grid, 256, 0, stream>>>(hb, wb, hp, N);
      } else {
        // hb already written by gather_kernel<0> in frag layout (F=256)
        cvt_w_kernel<256><<<(256 * 32 + 255) / 256, 256, 0, stream>>>(W[s][1], wb);
        gemm_mfma<256><<<gemm_grid, 256, 0, stream>>>(hb, wb, hp, N);
      }
      // 2. per-node attention logits
      attn_kernel<<<(nh + 255) / 256, 256, 0, stream>>>(hp, AS[s][l], AT[s][l],
                                                        attn_s, attn_t, nh);
      // 3. fused softmax + CSR gather + epilogue
      if (l == 0)
        gather_kernel<0><<<(N * 64 + 255) / 256, 256, 0, stream>>>(
            hp, attn_s, attn_t, csrc, row_ptr, nullptr, hb, N);
      else
        gather_kernel<1><<<(n_user * 64 + 255) / 256, 256, 0, stream>>>(
            hp, attn_s, attn_t, csrc, row_ptr, emb[s], nullptr, n_user);
    }
  }

  final_kernel<<<(n_user + 255) / 256, 256, 0, stream>>>(emb[0], emb[1], fc_w, fc_b,
                                                         out, n_user);
}